// Round 1
// baseline (179.384 us; speedup 1.0000x reference)
//
#include <hip/hip_runtime.h>

#define M 4096
#define L 32
#define K 64
#define NBLK 256
#define BLOCK 256
#define NPW 4                     // nodes per wave (4 waves -> 16 nodes/block)
#define NPB 16                    // nodes per block
#define MK (M * K)
#define FB 0xAAAAAAAAu            // ws poison; round tag = FB + round (r>=1)

// Persistent kernel (R8): dataflow-tagged exchange, NO barrier machinery.
// 256 blocks x 256 threads; wave w of block b owns nodes base..base+3,
// base = 16*b + 4*w; lane k owns in-edge k.
//
// Publish: node value as ONE tagged 8B sc1 store: (FB+r)<<32 | f32bits.
//   Aligned 8B stores are single-transaction: tag visible => value visible.
//   No RMW ack, no flags, no combiner, no release (R7's two-hop chain gone).
// Wait = restage: each thread sc1-loads its 16 strided u64s (coalesced
//   1KB/wave-instr), verifies hi-word == FB+r, re-loads only stale entries.
//   The poll IS the data read; straggler retries touch only stale lines.
// Versioning: double buffer (2 x 32KB). A block publishes r+1 only after
//   fully restaging r, which needs all blocks' r-publishes, which need their
//   (r-1)-restages -> blocks never 2 rounds apart -> 2 buffers suffice.
//   Tag equality rejects poison (FB+0) and stale rounds; no memset needed.
__global__ __launch_bounds__(BLOCK)
void net_kernel(const float* __restrict__ x,
                const float* __restrict__ w_in,
                const float* __restrict__ b_in,
                const float* __restrict__ w,
                const float* __restrict__ b,
                const int* __restrict__ igraf,
                float* __restrict__ out,
                unsigned long long* __restrict__ buf)   // 2 x M u64
{
    __shared__ float sv[M];   // previous-layer value vector (16 KB)

    const int tid  = threadIdx.x;
    const int blk  = blockIdx.x;
    const int wave = tid >> 6;
    const int lane = tid & 63;
    const int base = blk * NPB + wave * NPW;
    const bool lastblk = (blk == NBLK - 1);   // owns node M-1

    // Layer-0 fragment prefetch (4 nodes/wave; bias on lanes 0-3).
    float wv[NPW]; int iv[NPW]; float breg = 0.0f;
    {
        const size_t b0 = (size_t)base * K + (size_t)lane;
        #pragma unroll
        for (int j = 0; j < NPW; ++j) {
            wv[j] = w[b0 + (size_t)j * K];
            iv[j] = igraf[b0 + (size_t)j * K];
        }
        if (lane < NPW) breg = b[base + lane];
    }

    // v0 = relu(w_in * x + b_in): 4 float4 per thread.
    #pragma unroll
    for (int j = 0; j < 4; ++j) {
        const int idx = tid + j * BLOCK;
        const float4 x4 = ((const float4*)x)[idx];
        const float4 wi = ((const float4*)w_in)[idx];
        const float4 bi = ((const float4*)b_in)[idx];
        float4 r;
        r.x = fmaxf(fmaf(wi.x, x4.x, bi.x), 0.0f);
        r.y = fmaxf(fmaf(wi.y, x4.y, bi.y), 0.0f);
        r.z = fmaxf(fmaf(wi.z, x4.z, bi.z), 0.0f);
        r.w = fmaxf(fmaf(wi.w, x4.w, bi.w), 0.0f);
        ((float4*)sv)[idx] = r;
    }
    __syncthreads();

    for (int l = 0; l < L; ++l) {
        // Gather + product, 4 independent nodes.
        float p[NPW];
        #pragma unroll
        for (int j = 0; j < NPW; ++j) p[j] = wv[j] * sv[iv[j]];

        // 4 independent 64-lane butterfly reductions.
        #pragma unroll
        for (int j = 0; j < NPW; ++j) {
            #pragma unroll
            for (int off = 32; off > 0; off >>= 1)
                p[j] += __shfl_xor(p[j], off, 64);
        }

        // Lane j (j<4) finalizes node base+j.
        float pj = p[0];
        pj = (lane == 1) ? p[1] : pj;
        pj = (lane == 2) ? p[2] : pj;
        pj = (lane == 3) ? p[3] : pj;
        const float val = 1.0f / (1.0f + __expf(-(pj + breg)));

        if (l == L - 1) {
            // Only block 255 reaches l=31. Unique writer: wave 3 lane 3
            // -> node 255*16 + 3*4 + 3 = 4095.
            if (wave == 3 && lane == 3) out[0] = val;
            break;
        }

        const unsigned tag = FB + (unsigned)(l + 1);
        unsigned long long* bufr = buf + (size_t)((l + 1) & 1) * M;

        // ---- publish: tagged 8B store, self-validating, fire-and-forget ----
        if (lane < NPW) {
            const unsigned long long pk =
                ((unsigned long long)tag << 32) |
                (unsigned long long)__float_as_uint(val);
            __hip_atomic_store(&bufr[base + lane], pk,
                               __ATOMIC_RELAXED, __HIP_MEMORY_SCOPE_AGENT);
        }

        if ((l == L - 2) && !lastblk) return;  // all but block 255 done

        // Prefetch next layer (drains while we wait on tags).
        if ((l + 2 < L) || lastblk) {
            const size_t nb = (size_t)(l + 1) * MK + (size_t)base * K + (size_t)lane;
            #pragma unroll
            for (int j = 0; j < NPW; ++j) {
                wv[j] = w[nb + (size_t)j * K];
                iv[j] = igraf[nb + (size_t)j * K];
            }
            if (lane < NPW) breg = b[(l + 1) * M + base + lane];
        }

        // ---- restage pass 1: 16 strided u64/thread, coalesced sc1 loads ----
        unsigned long long vals[16];
        #pragma unroll
        for (int j = 0; j < 16; ++j)
            vals[j] = __hip_atomic_load(&bufr[tid + j * BLOCK],
                                        __ATOMIC_RELAXED,
                                        __HIP_MEMORY_SCOPE_AGENT);

        __syncthreads();   // all waves done gathering from OLD sv

        // ---- verify tags; re-load only stale entries ----
        for (;;) {
            bool ok = true;
            #pragma unroll
            for (int j = 0; j < 16; ++j) {
                if ((unsigned)(vals[j] >> 32) != tag) {
                    ok = false;
                    vals[j] = __hip_atomic_load(&bufr[tid + j * BLOCK],
                                                __ATOMIC_RELAXED,
                                                __HIP_MEMORY_SCOPE_AGENT);
                }
            }
            if (ok) break;
            __builtin_amdgcn_s_sleep(1);
        }

        // ---- write verified values into LDS ----
        #pragma unroll
        for (int j = 0; j < 16; ++j)
            sv[tid + j * BLOCK] = __uint_as_float((unsigned)vals[j]);
        __syncthreads();
    }
}

extern "C" void kernel_launch(void* const* d_in, const int* in_sizes, int n_in,
                              void* d_out, int out_size, void* d_ws, size_t ws_size,
                              hipStream_t stream) {
    const float* x     = (const float*)d_in[0];
    const float* w_in  = (const float*)d_in[1];
    const float* b_in  = (const float*)d_in[2];
    const float* wt    = (const float*)d_in[3];
    const float* b     = (const float*)d_in[4];
    const int*   igraf = (const int*)d_in[5];
    float*       out   = (float*)d_out;

    unsigned long long* buf = (unsigned long long*)d_ws;   // 2 x M x 8B = 64KB

    // No memset: poison hi-word = FB+0 never matches a round tag (FB+r, r>=1).
    hipLaunchKernelGGL(net_kernel, dim3(NBLK), dim3(BLOCK), 0, stream,
                       x, w_in, b_in, wt, b, igraf, out, buf);
    (void)in_sizes; (void)n_in; (void)out_size; (void)ws_size;
}